// Round 1
// baseline (115.916 us; speedup 1.0000x reference)
//
#include <hip/hip_runtime.h>

typedef __attribute__((ext_vector_type(8))) short bf16x8;
typedef __attribute__((ext_vector_type(4))) float f32x4;

#define FB_ROWB 8448                   // 66 cols * 128 B per LDS feature row
#define FB_SZ   50688                  // 6 rows
#define LDS_TOT (2 * FB_SZ + 2 * 8192) // 117760 B

static __device__ __forceinline__ unsigned short f2bf(float f) {
  union { float f; unsigned u; } v; v.f = f;
  unsigned r = v.u + 0x7fffu + ((v.u >> 16) & 1u);
  return (unsigned short)(r >> 16);
}

static __device__ __forceinline__ void gload16(const void* g, void* l) {
  __builtin_amdgcn_global_load_lds(
      (const __attribute__((address_space(1))) void*)g,
      (__attribute__((address_space(3))) void*)l, 16, 0, 0);
}

// ---------------- kernel P: pack weights ----------------
// wpk: [c(7)][tap(9)][co(64)][ci(64)] bf16, slot-swizzled: slot' = (ci>>3) ^ (co&7)
// chunk c == feature f: 0=silu(base), 1..3=cos(g), 4..6=sin(g)
__global__ void pack_w_k(const float* __restrict__ sb, const float* __restrict__ ss,
                         const float* __restrict__ cf, unsigned short* __restrict__ wpk) {
  int idx = blockIdx.x * 256 + threadIdx.x;
  if (idx >= 7 * 9 * 64 * 64) return;
  int ci = idx & 63;
  int co = (idx >> 6) & 63;
  int tap = (idx >> 12) % 9;
  int c = idx / 36864;
  int kh = tap / 3, kw = tap % 3;
  int wi = ((co * 64 + ci) * 3 + kh) * 3 + kw;   // [co][ci][kh][kw]
  float v;
  if (c == 0) {
    v = sb[wi];
  } else {
    int s = (c - 1) / 3, g = (c - 1) % 3;        // s: 0=cos 1=sin, g = harmonic-1
    v = cf[(s * 36864 + wi) * 3 + g] * ss[wi];
  }
  int slot = (tap * 64 + co) * 8 + ((ci >> 3) ^ (co & 7));
  wpk[c * 36864 + slot * 8 + (ci & 7)] = f2bf(v);
}

// ---------------- kernel F: feature expansion ----------------
// fg: [c(7)][b(32)][h(64)] rows of 8192 B = [w(64)][128 B chunk-slice],
// slice slot q holds feature-slot q ^ ((w+1)&7)  (pre-swizzle for GEMM LDS)
__global__ void feats_k(const float* __restrict__ x, unsigned short* __restrict__ fg) {
  __shared__ __align__(16) unsigned short lds[64 * 448]; // [w][record], swizzled
  const int b = blockIdx.x, h = blockIdx.y;
  const int tid = threadIdx.x;             // 256
  const int w = tid & 63, cig = tid >> 6;  // 4 groups x 16 ci
  const int key = (w + 1) & 7;
  const int base = w * 448;
#pragma unroll
  for (int i = 0; i < 16; ++i) {
    int ci = cig * 16 + i;
    float v = x[(((size_t)b * 64 + ci) * 64 + h) * 64 + w];
    float sg = 1.0f / (1.0f + __expf(-v));
    float f0 = v * sg;
    float s1, c1;
    __sincosf(v, &s1, &c1);
    float c2 = c1 * c1 - s1 * s1, s2 = 2.0f * s1 * c1;
    float c3 = c1 * c2 - s1 * s2, s3 = s1 * c2 + c1 * s2;
    int sl8 = ((ci >> 3) ^ key) << 3;
    int e = ci & 7;
    lds[base + 0 * 64 + sl8 + e] = f2bf(f0);
    lds[base + 1 * 64 + sl8 + e] = f2bf(c1);
    lds[base + 2 * 64 + sl8 + e] = f2bf(c2);
    lds[base + 3 * 64 + sl8 + e] = f2bf(c3);
    lds[base + 4 * 64 + sl8 + e] = f2bf(s1);
    lds[base + 5 * 64 + sl8 + e] = f2bf(s2);
    lds[base + 6 * 64 + sl8 + e] = f2bf(s3);
  }
  __syncthreads();
#pragma unroll
  for (int c = 0; c < 7; ++c) {
    unsigned short* dst = fg + ((size_t)(c * 32 + b) * 64 + h) * 4096;
#pragma unroll
    for (int k = 0; k < 2; ++k) {
      int idx = tid + k * 256;       // 16B units: [w(64)][slot(8)]
      int wp = idx >> 3, sl = idx & 7;
      uint4 v = *(const uint4*)&lds[wp * 448 + c * 64 + sl * 8];
      *(uint4*)&dst[(size_t)idx * 8] = v;
    }
  }
}

// ---------------- kernel G: implicit GEMM ----------------
// block: b = blockIdx.x, rows h0..h0+3 (h0 = blockIdx.y*4); M=256 pixels x N=64.
// 8 waves: wave wid owns pixels [wid*32, wid*32+32) (row wid>>1, half (wid&1)).
__global__ __launch_bounds__(512, 2) void gemm_k(
    const unsigned short* __restrict__ fg, const unsigned short* __restrict__ wpk,
    const float* __restrict__ bias, float* __restrict__ out) {
  extern __shared__ __align__(16) char smem[];
  char* fb0 = smem;
  char* fb1 = smem + FB_SZ;
  char* bb0 = smem + 2 * FB_SZ;
  char* bb1 = smem + 2 * FB_SZ + 8192;
  const int b = blockIdx.x;
  const int h0 = blockIdx.y * 4;
  const int tid = threadIdx.x;
  const int lane = tid & 63;
  const int wid = tid >> 6;

  // zero feature buffers: halo cols + out-of-range rows stay zero forever
  for (int i = tid; i < (2 * FB_SZ) / 4; i += 512) ((int*)smem)[i] = 0;
  __syncthreads();

#define STAGE_F(cc, dst)                                                         \
  {                                                                              \
    for (int j = 0; j < 6; ++j) {                                                \
      int seg = wid * 6 + j;                                                     \
      int lrow = seg >> 3, part = seg & 7;                                       \
      int hh = h0 - 1 + lrow;                                                    \
      if ((unsigned)hh < 64u) {                                                  \
        const char* g = (const char*)fg +                                        \
            ((size_t)(((cc) * 32 + b) * 64 + hh)) * 8192 + part * 1024 + lane * 16; \
        gload16(g, (dst) + lrow * FB_ROWB + 128 + part * 1024);                  \
      }                                                                          \
    }                                                                            \
  }
#define STAGE_B(itn, dst)                                                        \
  {                                                                              \
    const char* g = (const char*)wpk + (size_t)(itn) * 8192 + wid * 1024 + lane * 16; \
    gload16(g, (dst) + wid * 1024);                                              \
  }

  f32x4 acc[2][4];
#pragma unroll
  for (int mf = 0; mf < 2; ++mf)
#pragma unroll
    for (int nf = 0; nf < 4; ++nf)
#pragma unroll
      for (int q = 0; q < 4; ++q) acc[mf][nf][q] = 0.0f;

  STAGE_F(0, fb0);
  STAGE_B(0, bb0);
  __syncthreads();

  const int r = wid >> 1;
  const int wb = (wid & 1) * 32;
  const int l15 = lane & 15;
  const int lg = lane >> 4;

  for (int it = 0; it < 63; ++it) {
    int c = it / 9;
    int tap = it - c * 9;
    if (tap == 0 && c < 6) { char* d = ((c + 1) & 1) ? fb1 : fb0; STAGE_F(c + 1, d); }
    if (it < 62) { char* d = ((it + 1) & 1) ? bb1 : bb0; STAGE_B(it + 1, d); }
    const char* f = (c & 1) ? fb1 : fb0;
    const char* bbuf = (it & 1) ? bb1 : bb0;
    int kh = tap / 3, kw = tap - kh * 3;
    int lrow = r + kh;

    bf16x8 A[2][2];
#pragma unroll
    for (int mf = 0; mf < 2; ++mf) {
      int col = wb + mf * 16 + l15 + kw;       // LDS col = image w + kw (halo at 0/65)
      const char* rp = f + lrow * FB_ROWB + col * 128;
      int key = col & 7;
#pragma unroll
      for (int ks = 0; ks < 2; ++ks)
        A[mf][ks] = *(const bf16x8*)(rp + (((ks * 4 + lg) ^ key) << 4));
    }
    bf16x8 Bf[4][2];
#pragma unroll
    for (int nf = 0; nf < 4; ++nf) {
      int co = nf * 16 + l15;
      const char* rp = bbuf + co * 128;
      int key = co & 7;
#pragma unroll
      for (int ks = 0; ks < 2; ++ks)
        Bf[nf][ks] = *(const bf16x8*)(rp + (((ks * 4 + lg) ^ key) << 4));
    }
#pragma unroll
    for (int ks = 0; ks < 2; ++ks)
#pragma unroll
      for (int mf = 0; mf < 2; ++mf)
#pragma unroll
        for (int nf = 0; nf < 4; ++nf)
          acc[mf][nf] = __builtin_amdgcn_mfma_f32_16x16x32_bf16(
              A[mf][ks], Bf[nf][ks], acc[mf][nf], 0, 0, 0);
    __syncthreads();
  }

  // epilogue: C/D layout col=lane&15 (co), row=(lane>>4)*4+reg (pixel)
  const int hrow = h0 + r;
#pragma unroll
  for (int mf = 0; mf < 2; ++mf) {
    int w4 = wb + mf * 16 + (lg << 2);
#pragma unroll
    for (int nf = 0; nf < 4; ++nf) {
      int co = nf * 16 + l15;
      float bv = bias[co];
      f32x4 v = acc[mf][nf];
      f32x4 res;
      res[0] = v[0] + bv; res[1] = v[1] + bv; res[2] = v[2] + bv; res[3] = v[3] + bv;
      *(f32x4*)(out + ((size_t)(b * 64 + co) * 64 + hrow) * 64 + w4) = res;
    }
  }
#undef STAGE_F
#undef STAGE_B
}

// ---------------- fallback: naive fp32 direct (if ws too small) ----------------
__global__ void naive_k(const float* __restrict__ x, const float* __restrict__ sb,
                        const float* __restrict__ ss, const float* __restrict__ cf,
                        const float* __restrict__ bias, float* __restrict__ out) {
  int idx = blockIdx.x * 256 + threadIdx.x;
  if (idx >= 32 * 64 * 64 * 64) return;
  int w = idx & 63, h = (idx >> 6) & 63, co = (idx >> 12) & 63, b = idx >> 18;
  float acc = bias[co];
  for (int ci = 0; ci < 64; ++ci) {
    for (int kh = 0; kh < 3; ++kh) {
      int hh = h + kh - 1;
      if ((unsigned)hh >= 64u) continue;
      for (int kw = 0; kw < 3; ++kw) {
        int ww = w + kw - 1;
        if ((unsigned)ww >= 64u) continue;
        float v = x[((b * 64 + ci) * 64 + hh) * 64 + ww];
        int wi = ((co * 64 + ci) * 3 + kh) * 3 + kw;
        float s1, c1; __sincosf(v, &s1, &c1);
        float c2 = c1 * c1 - s1 * s1, s2 = 2.f * s1 * c1;
        float c3 = c1 * c2 - s1 * s2, s3 = s1 * c2 + c1 * s2;
        float t = sb[wi] * (v / (1.f + __expf(-v)));
        t += ss[wi] * (cf[wi * 3] * c1 + cf[wi * 3 + 1] * c2 + cf[wi * 3 + 2] * c3 +
                       cf[(36864 + wi) * 3] * s1 + cf[(36864 + wi) * 3 + 1] * s2 +
                       cf[(36864 + wi) * 3 + 2] * s3);
        acc += t;
      }
    }
  }
  out[idx] = acc;
}

extern "C" void kernel_launch(void* const* d_in, const int* in_sizes, int n_in,
                              void* d_out, int out_size, void* d_ws, size_t ws_size,
                              hipStream_t stream) {
  const float* x = (const float*)d_in[0];
  const float* sb = (const float*)d_in[1];
  const float* ss = (const float*)d_in[2];
  const float* cf = (const float*)d_in[3];
  const float* bias = (const float*)d_in[4];
  float* out = (float*)d_out;

  const size_t FEATS_OFF = 1u << 20;                        // wpk in first 1 MB
  const size_t NEED = FEATS_OFF + (size_t)7 * 32 * 64 * 8192; // ~118.4 MB
  if (ws_size >= NEED) {
    unsigned short* wpk = (unsigned short*)d_ws;
    unsigned short* fg = (unsigned short*)((char*)d_ws + FEATS_OFF);
    pack_w_k<<<1008, 256, 0, stream>>>(sb, ss, cf, wpk);
    feats_k<<<dim3(32, 64), 256, 0, stream>>>(x, fg);
    hipFuncSetAttribute((const void*)gemm_k,
                        hipFuncAttributeMaxDynamicSharedMemorySize, LDS_TOT);
    gemm_k<<<dim3(32, 16), 512, LDS_TOT, stream>>>(fg, wpk, bias, out);
  } else {
    naive_k<<<32768, 256, 0, stream>>>(x, sb, ss, cf, bias, out);
  }
}

// Round 2
// 115.748 us; speedup vs baseline: 1.0015x; 1.0015x over previous
//
#include <hip/hip_runtime.h>

typedef __attribute__((ext_vector_type(8))) short bf16x8;
typedef __attribute__((ext_vector_type(4))) float f32x4;

#define FROW   4224                    // 66 cols * 64 B per LDS feature row
#define FBUF   42240                   // 10 rows
#define BB0    (2 * FBUF)              // 84480
#define BB1    (2 * FBUF + 4096)
#define LDS_TOT (2 * FBUF + 2 * 4096)  // 92672 B

static __device__ __forceinline__ unsigned short f2bf(float f) {
  union { float f; unsigned u; } v; v.f = f;
  unsigned r = v.u + 0x7fffu + ((v.u >> 16) & 1u);
  return (unsigned short)(r >> 16);
}

static __device__ __forceinline__ void gload16(const void* g, void* l) {
  __builtin_amdgcn_global_load_lds(
      (const __attribute__((address_space(1))) void*)g,
      (__attribute__((address_space(3))) void*)l, 16, 0, 0);
}

// ---------------- kernel P: pack weights ----------------
// wpk: [it(126 = (c*2+half)*9+tap)][co(64)][slot(4)][8ci] bf16,
// slot' = slot ^ (co&3); unswizzled slot q holds ci = half*32 + q*8 + e.
__global__ void pack_w_k(const float* __restrict__ sb, const float* __restrict__ ss,
                         const float* __restrict__ cf, unsigned short* __restrict__ wpk) {
  int idx = blockIdx.x * 256 + threadIdx.x;
  if (idx >= 126 * 64 * 32) return;
  int e = idx & 7;
  int q = (idx >> 3) & 3;
  int co = (idx >> 5) & 63;
  int rest = idx >> 11;          // 0..1133
  int tap = rest % 9;
  int c2 = rest / 9;             // 0..13
  int c = c2 >> 1, half = c2 & 1;
  int ci = half * 32 + q * 8 + e;
  int kh = tap / 3, kw = tap % 3;
  int wi = ((co * 64 + ci) * 3 + kh) * 3 + kw;   // [co][ci][kh][kw]
  float v;
  if (c == 0) {
    v = sb[wi];
  } else {
    int s = (c - 1) / 3, g = (c - 1) % 3;        // s: 0=cos 1=sin
    v = cf[(s * 36864 + wi) * 3 + g] * ss[wi];
  }
  wpk[((c2 * 9 + tap) * 64 + co) * 32 + ((q ^ (co & 3)) << 3) + e] = f2bf(v);
}

// ---------------- kernel F: feature expansion ----------------
// fg: [c2(14)][b(32)][h(64)][w(64)][slot(4)][8ci] bf16 (4096 B per (c2,b,h) row),
// slot' = slot ^ ((w+1)&3); unswizzled slot q holds ci = half*32 + q*8 + e.
__global__ void feats_k(const float* __restrict__ x, unsigned short* __restrict__ fg) {
  __shared__ __align__(16) unsigned short lds[64 * 456]; // [w][c(7)][8 slots][8], stride padded
  const int b = blockIdx.x, h = blockIdx.y;
  const int tid = threadIdx.x;             // 256
  const int w = tid & 63, cig = tid >> 6;  // 4 groups x 16 ci
  const int key = (w + 1) & 3;
  const int base = w * 456;
#pragma unroll
  for (int i = 0; i < 16; ++i) {
    int ci = cig * 16 + i;
    float v = x[(((size_t)b * 64 + ci) * 64 + h) * 64 + w];
    float sg = 1.0f / (1.0f + __expf(-v));
    float f0 = v * sg;
    float s1, c1;
    __sincosf(v, &s1, &c1);
    float c2v = c1 * c1 - s1 * s1, s2v = 2.0f * s1 * c1;
    float c3v = c1 * c2v - s1 * s2v, s3v = s1 * c2v + c1 * s2v;
    int q = ci >> 3;                 // 0..7
    int half = q >> 2, qq = q & 3;
    int sl = (half * 4 + (qq ^ key)) * 8 + (ci & 7);
    lds[base + 0 * 64 + sl] = f2bf(f0);
    lds[base + 1 * 64 + sl] = f2bf(c1);
    lds[base + 2 * 64 + sl] = f2bf(c2v);
    lds[base + 3 * 64 + sl] = f2bf(c3v);
    lds[base + 4 * 64 + sl] = f2bf(s1);
    lds[base + 5 * 64 + sl] = f2bf(s2v);
    lds[base + 6 * 64 + sl] = f2bf(s3v);
  }
  __syncthreads();
  // copy out: records already swizzled in LDS; straight 16B copies
#pragma unroll
  for (int k = 0; k < 14; ++k) {
    int u = tid + k * 256;         // [c2(14)][w(64)][qs(4)]
    int qs = u & 3;
    int ww = (u >> 2) & 63;
    int c2i = u >> 8;
    int cc = c2i >> 1, half = c2i & 1;
    uint4 v = *(const uint4*)&lds[ww * 456 + cc * 64 + (half * 4 + qs) * 8];
    unsigned short* dst = fg + ((size_t)(c2i * 32 + b) * 64 + h) * 2048 + (ww * 4 + qs) * 8;
    *(uint4*)dst = v;
  }
}

// ---------------- kernel G: implicit GEMM ----------------
// grid (32 b, 8 hg) = 256 blocks = 1/CU. 8 waves; wave wid owns image row h0+wid,
// wave tile = 64 pixels x 64 cout. K staged as 14 half-chunks x 9 taps (K=32/iter).
__global__ __launch_bounds__(512, 2) void gemm_k(
    const unsigned short* __restrict__ fg, const unsigned short* __restrict__ wpk,
    const float* __restrict__ bias, float* __restrict__ out) {
  extern __shared__ __align__(16) char smem[];
  const int b = blockIdx.x;
  const int h0 = blockIdx.y * 8;
  const int tid = threadIdx.x;
  const int lane = tid & 63;
  const int wid = tid >> 6;
  const int l15 = lane & 15;
  const int lg = lane >> 4;
  const char* fgB = (const char*)fg;
  const char* wpkB = (const char*)wpk;

  // zero only bytes never staged: halo cols + out-of-range rows (both buffers)
  for (int i = tid; i < 2 * FBUF / 4; i += 512) {
    int off = i * 4;
    int off2 = (off >= FBUF) ? off - FBUF : off;
    int row = off2 / FROW;
    int cb = off2 - row * FROW;
    int hh = h0 - 1 + row;
    bool staged = ((unsigned)hh < 64u) && (cb >= 64) && (cb < 4160);
    if (!staged) ((int*)smem)[i] = 0;
  }

  // prologue: stage features c2=0 into fbuf0, B it=0 into bb0
  for (int k = wid; k < 40; k += 8) {
    int row = k >> 2, j = k & 3;
    int hh = h0 - 1 + row;
    if ((unsigned)hh < 64u)
      gload16(fgB + ((size_t)(b * 64 + hh)) * 4096 + j * 1024 + lane * 16,
              smem + row * FROW + 64 + j * 1024);
  }
  if (wid < 4)
    gload16(wpkB + wid * 1024 + lane * 16, smem + BB0 + wid * 1024);
  __syncthreads();

  f32x4 acc[4][4];
#pragma unroll
  for (int mf = 0; mf < 4; ++mf)
#pragma unroll
    for (int nf = 0; nf < 4; ++nf)
#pragma unroll
      for (int qq = 0; qq < 4; ++qq) acc[mf][nf][qq] = 0.0f;

  for (int c2 = 0; c2 < 14; ++c2) {
    const char* f = smem + ((c2 & 1) ? FBUF : 0);
    char* fnext = smem + (((c2 + 1) & 1) ? FBUF : 0);
#pragma unroll
    for (int tap = 0; tap < 9; ++tap) {
      const int it = c2 * 9 + tap;
      // stage next half-chunk's features, 5 calls per tap over taps 0..7
      if (tap < 8 && c2 < 13) {
#pragma unroll
        for (int i = 0; i < 5; ++i) {
          int k = tap * 5 + i;
          if ((k & 7) == wid) {
            int row = k >> 2, j = k & 3;
            int hh = h0 - 1 + row;
            if ((unsigned)hh < 64u)
              gload16(fgB + ((size_t)((c2 + 1) * 2048 + b * 64 + hh)) * 4096 +
                          j * 1024 + lane * 16,
                      fnext + row * FROW + 64 + j * 1024);
          }
        }
      }
      // stage next tap's B
      if (it < 125 && wid < 4)
        gload16(wpkB + (size_t)(it + 1) * 4096 + wid * 1024 + lane * 16,
                smem + (((it + 1) & 1) ? BB1 : BB0) + wid * 1024);

      const char* bb = smem + ((it & 1) ? BB1 : BB0);
      const int kh = tap / 3, kw = tap - kh * 3;
      const int lrow = wid + kh;

      bf16x8 A[4], Bv[4];
#pragma unroll
      for (int mf = 0; mf < 4; ++mf) {
        int col = mf * 16 + l15 + kw;            // LDS col = image w + kw (halo at 0/65)
        A[mf] = *(const bf16x8*)(f + (lrow * 66 + col) * 64 + ((lg ^ (col & 3)) << 4));
      }
#pragma unroll
      for (int nf = 0; nf < 4; ++nf) {
        int co = nf * 16 + l15;
        Bv[nf] = *(const bf16x8*)(bb + co * 64 + ((lg ^ (co & 3)) << 4));
      }
#pragma unroll
      for (int mf = 0; mf < 4; ++mf)
#pragma unroll
        for (int nf = 0; nf < 4; ++nf)
          acc[mf][nf] = __builtin_amdgcn_mfma_f32_16x16x32_bf16(
              A[mf], Bv[nf], acc[mf][nf], 0, 0, 0);
      __syncthreads();
    }
  }

  // epilogue: C/D layout col(lane&15)=co, row=(lane>>4)*4+reg = pixel w within frag
  const int h = h0 + wid;
#pragma unroll
  for (int mf = 0; mf < 4; ++mf) {
    int w4 = mf * 16 + (lg << 2);
#pragma unroll
    for (int nf = 0; nf < 4; ++nf) {
      int co = nf * 16 + l15;
      float bv = bias[co];
      f32x4 v = acc[mf][nf];
      f32x4 res;
      res[0] = v[0] + bv; res[1] = v[1] + bv; res[2] = v[2] + bv; res[3] = v[3] + bv;
      *(f32x4*)(out + ((size_t)(b * 64 + co) * 64 + h) * 64 + w4) = res;
    }
  }
}

// ---------------- fallback: naive fp32 direct (if ws too small) ----------------
__global__ void naive_k(const float* __restrict__ x, const float* __restrict__ sb,
                        const float* __restrict__ ss, const float* __restrict__ cf,
                        const float* __restrict__ bias, float* __restrict__ out) {
  int idx = blockIdx.x * 256 + threadIdx.x;
  if (idx >= 32 * 64 * 64 * 64) return;
  int w = idx & 63, h = (idx >> 6) & 63, co = (idx >> 12) & 63, b = idx >> 18;
  float acc = bias[co];
  for (int ci = 0; ci < 64; ++ci) {
    for (int kh = 0; kh < 3; ++kh) {
      int hh = h + kh - 1;
      if ((unsigned)hh >= 64u) continue;
      for (int kw = 0; kw < 3; ++kw) {
        int ww = w + kw - 1;
        if ((unsigned)ww >= 64u) continue;
        float v = x[((b * 64 + ci) * 64 + hh) * 64 + ww];
        int wi = ((co * 64 + ci) * 3 + kh) * 3 + kw;
        float s1, c1; __sincosf(v, &s1, &c1);
        float c2 = c1 * c1 - s1 * s1, s2 = 2.f * s1 * c1;
        float c3 = c1 * c2 - s1 * s2, s3 = s1 * c2 + c1 * s2;
        float t = sb[wi] * (v / (1.f + __expf(-v)));
        t += ss[wi] * (cf[wi * 3] * c1 + cf[wi * 3 + 1] * c2 + cf[wi * 3 + 2] * c3 +
                       cf[(36864 + wi) * 3] * s1 + cf[(36864 + wi) * 3 + 1] * s2 +
                       cf[(36864 + wi) * 3 + 2] * s3);
        acc += t;
      }
    }
  }
  out[idx] = acc;
}

extern "C" void kernel_launch(void* const* d_in, const int* in_sizes, int n_in,
                              void* d_out, int out_size, void* d_ws, size_t ws_size,
                              hipStream_t stream) {
  const float* x = (const float*)d_in[0];
  const float* sb = (const float*)d_in[1];
  const float* ss = (const float*)d_in[2];
  const float* cf = (const float*)d_in[3];
  const float* bias = (const float*)d_in[4];
  float* out = (float*)d_out;

  const size_t FEATS_OFF = 1u << 20;                          // wpk in first 1 MB
  const size_t NEED = FEATS_OFF + (size_t)14 * 32 * 64 * 4096; // ~118.5 MB
  if (ws_size >= NEED) {
    unsigned short* wpk = (unsigned short*)d_ws;
    unsigned short* fg = (unsigned short*)((char*)d_ws + FEATS_OFF);
    pack_w_k<<<1008, 256, 0, stream>>>(sb, ss, cf, wpk);
    feats_k<<<dim3(32, 64), 256, 0, stream>>>(x, fg);
    hipFuncSetAttribute((const void*)gemm_k,
                        hipFuncAttributeMaxDynamicSharedMemorySize, LDS_TOT);
    gemm_k<<<dim3(32, 8), 512, LDS_TOT, stream>>>(fg, wpk, bias, out);
  } else {
    naive_k<<<32768, 256, 0, stream>>>(x, sb, ss, cf, bias, out);
  }
}

// Round 3
// 107.397 us; speedup vs baseline: 1.0793x; 1.0778x over previous
//
#include <hip/hip_runtime.h>

typedef __attribute__((ext_vector_type(8))) short bf16x8;
typedef __attribute__((ext_vector_type(4))) float f32x4;

#define FROW   4224                    // 66 cols * 64 B per LDS feature row
#define FBUF   42240                   // 10 rows
#define BB0    (2 * FBUF)              // 84480
#define BB1    (2 * FBUF + 4096)
#define LDS_TOT (2 * FBUF + 2 * 4096)  // 92672 B

static __device__ __forceinline__ unsigned short f2bf(float f) {
  union { float f; unsigned u; } v; v.f = f;
  unsigned r = v.u + 0x7fffu + ((v.u >> 16) & 1u);
  return (unsigned short)(r >> 16);
}

static __device__ __forceinline__ void gload16(const void* g, void* l) {
  __builtin_amdgcn_global_load_lds(
      (const __attribute__((address_space(1))) void*)g,
      (__attribute__((address_space(3))) void*)l, 16, 0, 0);
}

// ---------------- kernel P: pack weights ----------------
// wpk: [it(126 = (c*2+half)*9+tap)][co(64)][slot(4)][8ci] bf16,
// slot' = slot ^ ((co>>1)&3); unswizzled slot q holds ci = half*32 + q*8 + e.
// Key uses (co>>1)&3 (period 8 in co) so each 8-consecutive-lane group of a
// ds_read_b128 hits all 8 16B-slots of a 128B window exactly once.
__global__ void pack_w_k(const float* __restrict__ sb, const float* __restrict__ ss,
                         const float* __restrict__ cf, unsigned short* __restrict__ wpk) {
  int idx = blockIdx.x * 256 + threadIdx.x;
  if (idx >= 126 * 64 * 32) return;
  int e = idx & 7;
  int q = (idx >> 3) & 3;
  int co = (idx >> 5) & 63;
  int rest = idx >> 11;          // 0..1133
  int tap = rest % 9;
  int c2 = rest / 9;             // 0..13
  int c = c2 >> 1, half = c2 & 1;
  int ci = half * 32 + q * 8 + e;
  int kh = tap / 3, kw = tap % 3;
  int wi = ((co * 64 + ci) * 3 + kh) * 3 + kw;   // [co][ci][kh][kw]
  float v;
  if (c == 0) {
    v = sb[wi];
  } else {
    int s = (c - 1) / 3, g = (c - 1) % 3;        // s: 0=cos 1=sin
    v = cf[(s * 36864 + wi) * 3 + g] * ss[wi];
  }
  wpk[((c2 * 9 + tap) * 64 + co) * 32 + ((q ^ ((co >> 1) & 3)) << 3) + e] = f2bf(v);
}

// ---------------- kernel F: feature expansion ----------------
// fg: [c2(14)][b(32)][h(64)][w(64)][slot(4)][8ci] bf16 (4096 B per (c2,b,h) row),
// slot' = slot ^ (((w+1)>>1)&3)  (LDS col = w+1 after halo shift; same key as read)
__global__ void feats_k(const float* __restrict__ x, unsigned short* __restrict__ fg) {
  __shared__ __align__(16) unsigned short lds[64 * 456]; // [w][c(7)][8 slots][8], stride padded
  const int b = blockIdx.x, h = blockIdx.y;
  const int tid = threadIdx.x;             // 256
  const int w = tid & 63, cig = tid >> 6;  // 4 groups x 16 ci
  const int key = ((w + 1) >> 1) & 3;
  const int base = w * 456;
#pragma unroll
  for (int i = 0; i < 16; ++i) {
    int ci = cig * 16 + i;
    float v = x[(((size_t)b * 64 + ci) * 64 + h) * 64 + w];
    float sg = 1.0f / (1.0f + __expf(-v));
    float f0 = v * sg;
    float s1, c1;
    __sincosf(v, &s1, &c1);
    float c2v = c1 * c1 - s1 * s1, s2v = 2.0f * s1 * c1;
    float c3v = c1 * c2v - s1 * s2v, s3v = s1 * c2v + c1 * s2v;
    int q = ci >> 3;                 // 0..7
    int half = q >> 2, qq = q & 3;
    int sl = (half * 4 + (qq ^ key)) * 8 + (ci & 7);
    lds[base + 0 * 64 + sl] = f2bf(f0);
    lds[base + 1 * 64 + sl] = f2bf(c1);
    lds[base + 2 * 64 + sl] = f2bf(c2v);
    lds[base + 3 * 64 + sl] = f2bf(c3v);
    lds[base + 4 * 64 + sl] = f2bf(s1);
    lds[base + 5 * 64 + sl] = f2bf(s2v);
    lds[base + 6 * 64 + sl] = f2bf(s3v);
  }
  __syncthreads();
  // copy out: records already swizzled in LDS; straight 16B copies
#pragma unroll
  for (int k = 0; k < 14; ++k) {
    int u = tid + k * 256;         // [c2(14)][w(64)][qs(4)]
    int qs = u & 3;
    int ww = (u >> 2) & 63;
    int c2i = u >> 8;
    int cc = c2i >> 1, half = c2i & 1;
    uint4 v = *(const uint4*)&lds[ww * 456 + cc * 64 + (half * 4 + qs) * 8];
    unsigned short* dst = fg + ((size_t)(c2i * 32 + b) * 64 + h) * 2048 + (ww * 4 + qs) * 8;
    *(uint4*)dst = v;
  }
}

// ---------------- kernel G: implicit GEMM ----------------
// grid (32 b, 8 hg) = 256 blocks = 1/CU. 8 waves; wave wid owns image row h0+wid,
// wave tile = 64 pixels x 64 cout. K staged as 14 half-chunks x 9 taps (K=32/iter).
__global__ __launch_bounds__(512, 2) void gemm_k(
    const unsigned short* __restrict__ fg, const unsigned short* __restrict__ wpk,
    const float* __restrict__ bias, float* __restrict__ out) {
  extern __shared__ __align__(16) char smem[];
  const int b = blockIdx.x;
  const int h0 = blockIdx.y * 8;
  const int tid = threadIdx.x;
  const int lane = tid & 63;
  const int wid = tid >> 6;
  const int l15 = lane & 15;
  const int lg = lane >> 4;
  const char* fgB = (const char*)fg;
  const char* wpkB = (const char*)wpk;

  // zero only bytes never staged: halo cols + out-of-range rows (both buffers)
  for (int i = tid; i < 2 * FBUF / 4; i += 512) {
    int off = i * 4;
    int off2 = (off >= FBUF) ? off - FBUF : off;
    int row = off2 / FROW;
    int cb = off2 - row * FROW;
    int hh = h0 - 1 + row;
    bool staged = ((unsigned)hh < 64u) && (cb >= 64) && (cb < 4160);
    if (!staged) ((int*)smem)[i] = 0;
  }

  // prologue: stage features c2=0 into fbuf0, B it=0 into bb0
  for (int k = wid; k < 40; k += 8) {
    int row = k >> 2, j = k & 3;
    int hh = h0 - 1 + row;
    if ((unsigned)hh < 64u)
      gload16(fgB + ((size_t)(b * 64 + hh)) * 4096 + j * 1024 + lane * 16,
              smem + row * FROW + 64 + j * 1024);
  }
  if (wid < 4)
    gload16(wpkB + wid * 1024 + lane * 16, smem + BB0 + wid * 1024);
  __syncthreads();

  f32x4 acc[4][4];
#pragma unroll
  for (int mf = 0; mf < 4; ++mf)
#pragma unroll
    for (int nf = 0; nf < 4; ++nf)
#pragma unroll
      for (int qq = 0; qq < 4; ++qq) acc[mf][nf][qq] = 0.0f;

  for (int c2 = 0; c2 < 14; ++c2) {
    const char* f = smem + ((c2 & 1) ? FBUF : 0);
    char* fnext = smem + (((c2 + 1) & 1) ? FBUF : 0);
#pragma unroll
    for (int tap = 0; tap < 9; ++tap) {
      const int it = c2 * 9 + tap;
      // stage next half-chunk's features, 5 calls per tap over taps 0..7
      if (tap < 8 && c2 < 13) {
#pragma unroll
        for (int i = 0; i < 5; ++i) {
          int k = tap * 5 + i;
          if ((k & 7) == wid) {
            int row = k >> 2, j = k & 3;
            int hh = h0 - 1 + row;
            if ((unsigned)hh < 64u)
              gload16(fgB + ((size_t)((c2 + 1) * 2048 + b * 64 + hh)) * 4096 +
                          j * 1024 + lane * 16,
                      fnext + row * FROW + 64 + j * 1024);
          }
        }
      }
      // stage next tap's B
      if (it < 125 && wid < 4)
        gload16(wpkB + (size_t)(it + 1) * 4096 + wid * 1024 + lane * 16,
                smem + (((it + 1) & 1) ? BB1 : BB0) + wid * 1024);

      const char* bb = smem + ((it & 1) ? BB1 : BB0);
      const int kh = tap / 3, kw = tap - kh * 3;
      const int lrow = wid + kh;

      bf16x8 A[4], Bv[4];
#pragma unroll
      for (int mf = 0; mf < 4; ++mf) {
        int col = mf * 16 + l15 + kw;            // LDS col = image w + kw (halo at 0/65)
        A[mf] = *(const bf16x8*)(f + (lrow * 66 + col) * 64 + ((lg ^ ((col >> 1) & 3)) << 4));
      }
#pragma unroll
      for (int nf = 0; nf < 4; ++nf) {
        int co = nf * 16 + l15;
        Bv[nf] = *(const bf16x8*)(bb + co * 64 + ((lg ^ ((co >> 1) & 3)) << 4));
      }
#pragma unroll
      for (int mf = 0; mf < 4; ++mf)
#pragma unroll
        for (int nf = 0; nf < 4; ++nf)
          acc[mf][nf] = __builtin_amdgcn_mfma_f32_16x16x32_bf16(
              A[mf], Bv[nf], acc[mf][nf], 0, 0, 0);
      __syncthreads();
    }
  }

  // epilogue: C/D layout col(lane&15)=co, row=(lane>>4)*4+reg = pixel w within frag
  const int h = h0 + wid;
#pragma unroll
  for (int mf = 0; mf < 4; ++mf) {
    int w4 = mf * 16 + (lg << 2);
#pragma unroll
    for (int nf = 0; nf < 4; ++nf) {
      int co = nf * 16 + l15;
      float bv = bias[co];
      f32x4 v = acc[mf][nf];
      f32x4 res;
      res[0] = v[0] + bv; res[1] = v[1] + bv; res[2] = v[2] + bv; res[3] = v[3] + bv;
      *(f32x4*)(out + ((size_t)(b * 64 + co) * 64 + h) * 64 + w4) = res;
    }
  }
}

// ---------------- fallback: naive fp32 direct (if ws too small) ----------------
__global__ void naive_k(const float* __restrict__ x, const float* __restrict__ sb,
                        const float* __restrict__ ss, const float* __restrict__ cf,
                        const float* __restrict__ bias, float* __restrict__ out) {
  int idx = blockIdx.x * 256 + threadIdx.x;
  if (idx >= 32 * 64 * 64 * 64) return;
  int w = idx & 63, h = (idx >> 6) & 63, co = (idx >> 12) & 63, b = idx >> 18;
  float acc = bias[co];
  for (int ci = 0; ci < 64; ++ci) {
    for (int kh = 0; kh < 3; ++kh) {
      int hh = h + kh - 1;
      if ((unsigned)hh >= 64u) continue;
      for (int kw = 0; kw < 3; ++kw) {
        int ww = w + kw - 1;
        if ((unsigned)ww >= 64u) continue;
        float v = x[((b * 64 + ci) * 64 + hh) * 64 + ww];
        int wi = ((co * 64 + ci) * 3 + kh) * 3 + kw;
        float s1, c1; __sincosf(v, &s1, &c1);
        float c2 = c1 * c1 - s1 * s1, s2 = 2.f * s1 * c1;
        float c3 = c1 * c2 - s1 * s2, s3 = s1 * c2 + c1 * s2;
        float t = sb[wi] * (v / (1.f + __expf(-v)));
        t += ss[wi] * (cf[wi * 3] * c1 + cf[wi * 3 + 1] * c2 + cf[wi * 3 + 2] * c3 +
                       cf[(36864 + wi) * 3] * s1 + cf[(36864 + wi) * 3 + 1] * s2 +
                       cf[(36864 + wi) * 3 + 2] * s3);
        acc += t;
      }
    }
  }
  out[idx] = acc;
}

extern "C" void kernel_launch(void* const* d_in, const int* in_sizes, int n_in,
                              void* d_out, int out_size, void* d_ws, size_t ws_size,
                              hipStream_t stream) {
  const float* x = (const float*)d_in[0];
  const float* sb = (const float*)d_in[1];
  const float* ss = (const float*)d_in[2];
  const float* cf = (const float*)d_in[3];
  const float* bias = (const float*)d_in[4];
  float* out = (float*)d_out;

  const size_t FEATS_OFF = 1u << 20;                          // wpk in first 1 MB
  const size_t NEED = FEATS_OFF + (size_t)14 * 32 * 64 * 4096; // ~118.5 MB
  if (ws_size >= NEED) {
    unsigned short* wpk = (unsigned short*)d_ws;
    unsigned short* fg = (unsigned short*)((char*)d_ws + FEATS_OFF);
    pack_w_k<<<1008, 256, 0, stream>>>(sb, ss, cf, wpk);
    feats_k<<<dim3(32, 64), 256, 0, stream>>>(x, fg);
    hipFuncSetAttribute((const void*)gemm_k,
                        hipFuncAttributeMaxDynamicSharedMemorySize, LDS_TOT);
    gemm_k<<<dim3(32, 8), 512, LDS_TOT, stream>>>(fg, wpk, bias, out);
  } else {
    naive_k<<<32768, 256, 0, stream>>>(x, sb, ss, cf, bias, out);
  }
}

// Round 5
// 98.193 us; speedup vs baseline: 1.1805x; 1.0937x over previous
//
#include <hip/hip_runtime.h>

typedef __attribute__((ext_vector_type(8))) short bf16x8;
typedef __attribute__((ext_vector_type(4))) float f32x4;

#define FROW   4224                    // 66 cols * 64 B per LDS feature row
#define FBUF   42240                   // 10 rows
#define BGRP   36864                   // 9 taps * 4096 B
#define LDS_TOT (2 * FBUF + 2 * BGRP)  // 158208 B

static __device__ __forceinline__ unsigned short f2bf(float f) {
  union { float f; unsigned u; } v; v.f = f;
  unsigned r = v.u + 0x7fffu + ((v.u >> 16) & 1u);
  return (unsigned short)(r >> 16);
}

static __device__ __forceinline__ void gload16(const void* g, void* l) {
  __builtin_amdgcn_global_load_lds(
      (const __attribute__((address_space(1))) void*)g,
      (__attribute__((address_space(3))) void*)l, 16, 0, 0);
}

// ---------------- kernel P: pack weights ----------------
// wpk: [it(126 = c2*9+tap)][co(64)][slot(4)][8ci] bf16,
// slot' = slot ^ ((co>>1)&3); unswizzled slot q holds ci = half*32 + q*8 + e.
__global__ void pack_w_k(const float* __restrict__ sb, const float* __restrict__ ss,
                         const float* __restrict__ cf, unsigned short* __restrict__ wpk) {
  int idx = blockIdx.x * 256 + threadIdx.x;
  if (idx >= 126 * 64 * 32) return;
  int e = idx & 7;
  int q = (idx >> 3) & 3;
  int co = (idx >> 5) & 63;
  int rest = idx >> 11;          // 0..1133
  int tap = rest % 9;
  int c2 = rest / 9;             // 0..13
  int c = c2 >> 1, half = c2 & 1;
  int ci = half * 32 + q * 8 + e;
  int kh = tap / 3, kw = tap % 3;
  int wi = ((co * 64 + ci) * 3 + kh) * 3 + kw;   // [co][ci][kh][kw]
  float v;
  if (c == 0) {
    v = sb[wi];
  } else {
    int s = (c - 1) / 3, g = (c - 1) % 3;        // s: 0=cos 1=sin
    v = cf[(s * 36864 + wi) * 3 + g] * ss[wi];
  }
  wpk[((c2 * 9 + tap) * 64 + co) * 32 + ((q ^ ((co >> 1) & 3)) << 3) + e] = f2bf(v);
}

// ---------------- kernel F: feature expansion ----------------
// fg: [c2(14)][b(32)][h(64)][w(64)][slot(4)][8ci] bf16 (4096 B per (c2,b,h) row),
// slot' = slot ^ (((w+1)>>1)&3)  (LDS col = w+1 after halo shift; same key as read)
__global__ void feats_k(const float* __restrict__ x, unsigned short* __restrict__ fg) {
  __shared__ __align__(16) unsigned short lds[64 * 456]; // [w][c(7)][8 slots][8], stride padded
  const int b = blockIdx.x, h = blockIdx.y;
  const int tid = threadIdx.x;             // 256
  const int w = tid & 63, cig = tid >> 6;  // 4 groups x 16 ci
  const int key = ((w + 1) >> 1) & 3;
  const int base = w * 456;
#pragma unroll
  for (int i = 0; i < 16; ++i) {
    int ci = cig * 16 + i;
    float v = x[(((size_t)b * 64 + ci) * 64 + h) * 64 + w];
    float sg = 1.0f / (1.0f + __expf(-v));
    float f0 = v * sg;
    float s1, c1;
    __sincosf(v, &s1, &c1);
    float c2v = c1 * c1 - s1 * s1, s2v = 2.0f * s1 * c1;
    float c3v = c1 * c2v - s1 * s2v, s3v = s1 * c2v + c1 * s2v;
    int q = ci >> 3;                 // 0..7
    int half = q >> 2, qq = q & 3;
    int sl = (half * 4 + (qq ^ key)) * 8 + (ci & 7);
    lds[base + 0 * 64 + sl] = f2bf(f0);
    lds[base + 1 * 64 + sl] = f2bf(c1);
    lds[base + 2 * 64 + sl] = f2bf(c2v);
    lds[base + 3 * 64 + sl] = f2bf(c3v);
    lds[base + 4 * 64 + sl] = f2bf(s1);
    lds[base + 5 * 64 + sl] = f2bf(s2v);
    lds[base + 6 * 64 + sl] = f2bf(s3v);
  }
  __syncthreads();
#pragma unroll
  for (int k = 0; k < 14; ++k) {
    int u = tid + k * 256;         // [c2(14)][w(64)][qs(4)]
    int qs = u & 3;
    int ww = (u >> 2) & 63;
    int c2i = u >> 8;
    int cc = c2i >> 1, half = c2i & 1;
    uint4 v = *(const uint4*)&lds[ww * 456 + cc * 64 + (half * 4 + qs) * 8];
    unsigned short* dst = fg + ((size_t)(c2i * 32 + b) * 64 + h) * 2048 + (ww * 4 + qs) * 8;
    *(uint4*)dst = v;
  }
}

// ---------------- kernel G: implicit GEMM ----------------
// grid (32 b, 8 hg) = 256 blocks = 1/CU. 8 waves; wave wid owns image row h0+wid,
// wave tile = 64 pixels x 64 cout. One barrier per c2-chunk (15 total):
// per c2, stage features+9-tap B-group for c2+1, compute 9 taps, barrier.
__global__ __launch_bounds__(512, 2) void gemm_k(
    const unsigned short* __restrict__ fg, const unsigned short* __restrict__ wpk,
    const float* __restrict__ bias, float* __restrict__ out) {
  extern __shared__ __align__(16) char smem[];
  const int b = blockIdx.x;
  const int h0 = blockIdx.y * 8;
  const int tid = threadIdx.x;
  const int lane = tid & 63;
  const int wid = tid >> 6;
  const int l15 = lane & 15;
  const int lg = lane >> 4;
  const char* fgB = (const char*)fg;
  const char* wpkB = (const char*)wpk;

  // zero bytes never staged: halo cols + out-of-range rows (both feature buffers)
  for (int i = tid; i < 2 * FBUF / 4; i += 512) {
    int off = i * 4;
    int off2 = (off >= FBUF) ? off - FBUF : off;
    int row = off2 / FROW;
    int cb = off2 - row * FROW;
    int hh = h0 - 1 + row;
    bool staged = ((unsigned)hh < 64u) && (cb >= 64) && (cb < 4160);
    if (!staged) ((int*)smem)[i] = 0;
  }

  // staging helper: u 0..39 = feature row/quarter, 40..75 = B tap/part
#define STAGE_GRP(cn, fdst, bdst)                                                \
  for (int u = wid; u < 76; u += 8) {                                            \
    if (u < 40) {                                                                \
      int row = u >> 2, j = u & 3;                                               \
      int hh = h0 - 1 + row;                                                     \
      if ((unsigned)hh < 64u)                                                    \
        gload16(fgB + ((size_t)((cn) * 2048 + b * 64 + hh)) * 4096 +             \
                    j * 1024 + lane * 16,                                        \
                (fdst) + row * FROW + 64 + j * 1024);                            \
    } else {                                                                     \
      int t = u - 40;                                                            \
      int tap = t >> 2, part = t & 3;                                            \
      gload16(wpkB + (size_t)((cn) * 9 + tap) * 4096 + part * 1024 + lane * 16,  \
              (bdst) + tap * 4096 + part * 1024);                                \
    }                                                                            \
  }

  STAGE_GRP(0, smem, smem + 2 * FBUF);
  __syncthreads();

  f32x4 acc[4][4];
#pragma unroll
  for (int mf = 0; mf < 4; ++mf)
#pragma unroll
    for (int nf = 0; nf < 4; ++nf)
#pragma unroll
      for (int qq = 0; qq < 4; ++qq) acc[mf][nf][qq] = 0.0f;

  for (int c2 = 0; c2 < 14; ++c2) {
    const int cur = c2 & 1;
    char* f = smem + (cur ? FBUF : 0);
    char* bgc = smem + 2 * FBUF + (cur ? BGRP : 0);
    if (c2 < 13) {
      char* fnext = smem + (cur ? 0 : FBUF);
      char* bnext = smem + 2 * FBUF + (cur ? 0 : BGRP);
      STAGE_GRP(c2 + 1, fnext, bnext);
    }
#pragma unroll
    for (int tap = 0; tap < 9; ++tap) {
      const int kh = tap / 3, kw = tap - kh * 3;
      const int lrow = wid + kh;
      const char* bb = bgc + tap * 4096;

      bf16x8 A[4], Bv[4];
#pragma unroll
      for (int mf = 0; mf < 4; ++mf) {
        int col = mf * 16 + l15 + kw;            // LDS col = image w + kw (halo at 0/65)
        A[mf] = *(const bf16x8*)(f + (lrow * 66 + col) * 64 + ((lg ^ ((col >> 1) & 3)) << 4));
      }
#pragma unroll
      for (int nf = 0; nf < 4; ++nf) {
        int co = nf * 16 + l15;
        Bv[nf] = *(const bf16x8*)(bb + co * 64 + ((lg ^ ((co >> 1) & 3)) << 4));
      }
#pragma unroll
      for (int mf = 0; mf < 4; ++mf)
#pragma unroll
        for (int nf = 0; nf < 4; ++nf)
          acc[mf][nf] = __builtin_amdgcn_mfma_f32_16x16x32_bf16(
              A[mf], Bv[nf], acc[mf][nf], 0, 0, 0);
    }
    __syncthreads();
  }
#undef STAGE_GRP

  // epilogue: C/D layout col(lane&15)=co, row=(lane>>4)*4+reg = pixel w within frag
  const int h = h0 + wid;
#pragma unroll
  for (int mf = 0; mf < 4; ++mf) {
    int w4 = mf * 16 + (lg << 2);
#pragma unroll
    for (int nf = 0; nf < 4; ++nf) {
      int co = nf * 16 + l15;
      float bv = bias[co];
      f32x4 v = acc[mf][nf];
      f32x4 res;
      res[0] = v[0] + bv; res[1] = v[1] + bv; res[2] = v[2] + bv; res[3] = v[3] + bv;
      *(f32x4*)(out + ((size_t)(b * 64 + co) * 64 + h) * 64 + w4) = res;
    }
  }
}

// ---------------- fallback: naive fp32 direct (if ws too small) ----------------
__global__ void naive_k(const float* __restrict__ x, const float* __restrict__ sb,
                        const float* __restrict__ ss, const float* __restrict__ cf,
                        const float* __restrict__ bias, float* __restrict__ out) {
  int idx = blockIdx.x * 256 + threadIdx.x;
  if (idx >= 32 * 64 * 64 * 64) return;
  int w = idx & 63, h = (idx >> 6) & 63, co = (idx >> 12) & 63, b = idx >> 18;
  float acc = bias[co];
  for (int ci = 0; ci < 64; ++ci) {
    for (int kh = 0; kh < 3; ++kh) {
      int hh = h + kh - 1;
      if ((unsigned)hh >= 64u) continue;
      for (int kw = 0; kw < 3; ++kw) {
        int ww = w + kw - 1;
        if ((unsigned)ww >= 64u) continue;
        float v = x[((b * 64 + ci) * 64 + hh) * 64 + ww];
        int wi = ((co * 64 + ci) * 3 + kh) * 3 + kw;
        float s1, c1; __sincosf(v, &s1, &c1);
        float c2 = c1 * c1 - s1 * s1, s2 = 2.f * s1 * c1;
        float c3 = c1 * c2 - s1 * s2, s3 = s1 * c2 + c1 * s2;
        float t = sb[wi] * (v / (1.f + __expf(-v)));
        t += ss[wi] * (cf[wi * 3] * c1 + cf[wi * 3 + 1] * c2 + cf[wi * 3 + 2] * c3 +
                       cf[(36864 + wi) * 3] * s1 + cf[(36864 + wi) * 3 + 1] * s2 +
                       cf[(36864 + wi) * 3 + 2] * s3);
        acc += t;
      }
    }
  }
  out[idx] = acc;
}

extern "C" void kernel_launch(void* const* d_in, const int* in_sizes, int n_in,
                              void* d_out, int out_size, void* d_ws, size_t ws_size,
                              hipStream_t stream) {
  const float* x = (const float*)d_in[0];
  const float* sb = (const float*)d_in[1];
  const float* ss = (const float*)d_in[2];
  const float* cf = (const float*)d_in[3];
  const float* bias = (const float*)d_in[4];
  float* out = (float*)d_out;

  const size_t FEATS_OFF = 1u << 20;                          // wpk in first 1 MB
  const size_t NEED = FEATS_OFF + (size_t)14 * 32 * 64 * 4096; // ~118.5 MB
  if (ws_size >= NEED) {
    unsigned short* wpk = (unsigned short*)d_ws;
    unsigned short* fg = (unsigned short*)((char*)d_ws + FEATS_OFF);
    pack_w_k<<<1008, 256, 0, stream>>>(sb, ss, cf, wpk);
    feats_k<<<dim3(32, 64), 256, 0, stream>>>(x, fg);
    (void)hipFuncSetAttribute((const void*)gemm_k,
                              hipFuncAttributeMaxDynamicSharedMemorySize, LDS_TOT);
    gemm_k<<<dim3(32, 8), 512, LDS_TOT, stream>>>(fg, wpk, bias, out);
  } else {
    naive_k<<<32768, 256, 0, stream>>>(x, sb, ss, cf, bias, out);
  }
}

// Round 6
// 97.514 us; speedup vs baseline: 1.1887x; 1.0070x over previous
//
#include <hip/hip_runtime.h>

typedef __attribute__((ext_vector_type(8))) short bf16x8;
typedef __attribute__((ext_vector_type(4))) float f32x4;

#define FROW   4224                    // 66 cols * 64 B per LDS feature row
#define FBUF   42240                   // 10 rows
#define BGRP   36864                   // 9 taps * 4096 B
#define LDS_TOT (2 * FBUF + 2 * BGRP)  // 158208 B

static __device__ __forceinline__ unsigned short f2bf(float f) {
  union { float f; unsigned u; } v; v.f = f;
  unsigned r = v.u + 0x7fffu + ((v.u >> 16) & 1u);
  return (unsigned short)(r >> 16);
}

static __device__ __forceinline__ void gload16(const void* g, void* l) {
  __builtin_amdgcn_global_load_lds(
      (const __attribute__((address_space(1))) void*)g,
      (__attribute__((address_space(3))) void*)l, 16, 0, 0);
}

// ---------------- kernel P: pack weights ----------------
// wpk: [it(126 = c2*9+tap)][co(64)][slot(4)][8ci] bf16,
// slot' = slot ^ ((co>>1)&3); unswizzled slot q holds ci = half*32 + q*8 + e.
__global__ void pack_w_k(const float* __restrict__ sb, const float* __restrict__ ss,
                         const float* __restrict__ cf, unsigned short* __restrict__ wpk) {
  int idx = blockIdx.x * 256 + threadIdx.x;
  if (idx >= 126 * 64 * 32) return;
  int e = idx & 7;
  int q = (idx >> 3) & 3;
  int co = (idx >> 5) & 63;
  int rest = idx >> 11;          // 0..1133
  int tap = rest % 9;
  int c2 = rest / 9;             // 0..13
  int c = c2 >> 1, half = c2 & 1;
  int ci = half * 32 + q * 8 + e;
  int kh = tap / 3, kw = tap % 3;
  int wi = ((co * 64 + ci) * 3 + kh) * 3 + kw;   // [co][ci][kh][kw]
  float v;
  if (c == 0) {
    v = sb[wi];
  } else {
    int s = (c - 1) / 3, g = (c - 1) % 3;        // s: 0=cos 1=sin
    v = cf[(s * 36864 + wi) * 3 + g] * ss[wi];
  }
  wpk[((c2 * 9 + tap) * 64 + co) * 32 + ((q ^ ((co >> 1) & 3)) << 3) + e] = f2bf(v);
}

// ---------------- kernel F: feature expansion ----------------
// fg: [c2(14)][b(32)][h(64)][w(64)][slot(4)][8ci] bf16 (4096 B per (c2,b,h) row),
// slot' = slot ^ (((w+1)>>1)&3)  (LDS col = w+1 after halo shift; same key as read)
__global__ void feats_k(const float* __restrict__ x, unsigned short* __restrict__ fg) {
  __shared__ __align__(16) unsigned short lds[64 * 456]; // [w][c(7)][8 slots][8], stride padded
  const int b = blockIdx.x, h = blockIdx.y;
  const int tid = threadIdx.x;             // 256
  const int w = tid & 63, cig = tid >> 6;  // 4 groups x 16 ci
  const int key = ((w + 1) >> 1) & 3;
  const int base = w * 456;
#pragma unroll
  for (int i = 0; i < 16; ++i) {
    int ci = cig * 16 + i;
    float v = x[(((size_t)b * 64 + ci) * 64 + h) * 64 + w];
    float sg = 1.0f / (1.0f + __expf(-v));
    float f0 = v * sg;
    float s1, c1;
    __sincosf(v, &s1, &c1);
    float c2v = c1 * c1 - s1 * s1, s2v = 2.0f * s1 * c1;
    float c3v = c1 * c2v - s1 * s2v, s3v = s1 * c2v + c1 * s2v;
    int q = ci >> 3;                 // 0..7
    int half = q >> 2, qq = q & 3;
    int sl = (half * 4 + (qq ^ key)) * 8 + (ci & 7);
    lds[base + 0 * 64 + sl] = f2bf(f0);
    lds[base + 1 * 64 + sl] = f2bf(c1);
    lds[base + 2 * 64 + sl] = f2bf(c2v);
    lds[base + 3 * 64 + sl] = f2bf(c3v);
    lds[base + 4 * 64 + sl] = f2bf(s1);
    lds[base + 5 * 64 + sl] = f2bf(s2v);
    lds[base + 6 * 64 + sl] = f2bf(s3v);
  }
  __syncthreads();
#pragma unroll
  for (int k = 0; k < 14; ++k) {
    int u = tid + k * 256;         // [c2(14)][w(64)][qs(4)]
    int qs = u & 3;
    int ww = (u >> 2) & 63;
    int c2i = u >> 8;
    int cc = c2i >> 1, half = c2i & 1;
    uint4 v = *(const uint4*)&lds[ww * 456 + cc * 64 + (half * 4 + qs) * 8];
    unsigned short* dst = fg + ((size_t)(c2i * 32 + b) * 64 + h) * 2048 + (ww * 4 + qs) * 8;
    *(uint4*)dst = v;
  }
}

// ---------------- kernel G: implicit GEMM ----------------
// grid (32 b, 8 hg) = 256 blocks = 1/CU. 8 waves in 2 K-groups (tap-split):
// waves 0-3 do taps 0-4, waves 4-7 taps 5-8. Each wave: M=128 px (2 image
// rows) x 64 cout, acc[2][4][4]. Cross-group f32 reduction via LDS at end.
__global__ __launch_bounds__(512, 2) void gemm_k(
    const unsigned short* __restrict__ fg, const unsigned short* __restrict__ wpk,
    const float* __restrict__ bias, float* __restrict__ out) {
  extern __shared__ __align__(16) char smem[];
  const int b = blockIdx.x;
  const int h0 = blockIdx.y * 8;
  const int tid = threadIdx.x;
  const int lane = tid & 63;
  const int wid = tid >> 6;
  const int l15 = lane & 15;
  const int lg = lane >> 4;
  const int grp = wid >> 2;          // 0: taps 0-4, 1: taps 5-8
  const int rowb = (wid & 3) * 2;    // wave's first image row within block
  const char* fgB = (const char*)fg;
  const char* wpkB = (const char*)wpk;

  // zero bytes never staged: halo cols + out-of-range rows (both feature buffers)
  for (int i = tid; i < 2 * FBUF / 4; i += 512) {
    int off = i * 4;
    int off2 = (off >= FBUF) ? off - FBUF : off;
    int row = off2 / FROW;
    int cb = off2 - row * FROW;
    int hh = h0 - 1 + row;
    bool staged = ((unsigned)hh < 64u) && (cb >= 64) && (cb < 4160);
    if (!staged) ((int*)smem)[i] = 0;
  }

  // precomputed swizzled LDS offsets (hoists XOR math out of the tap loop)
  int aoff[4][3], boff[4];
#pragma unroll
  for (int cf = 0; cf < 4; ++cf) {
#pragma unroll
    for (int kw = 0; kw < 3; ++kw) {
      int col = cf * 16 + l15 + kw;
      aoff[cf][kw] = col * 64 + ((lg ^ ((col >> 1) & 3)) << 4);
    }
    int co = cf * 16 + l15;
    boff[cf] = co * 64 + ((lg ^ ((co >> 1) & 3)) << 4);
  }

  // staging helper: u 0..39 = feature row/quarter, 40..75 = B tap/part
#define STAGE_GRP(cn, fdst, bdst)                                                \
  for (int u = wid; u < 76; u += 8) {                                            \
    if (u < 40) {                                                                \
      int row = u >> 2, j = u & 3;                                               \
      int hh = h0 - 1 + row;                                                     \
      if ((unsigned)hh < 64u)                                                    \
        gload16(fgB + ((size_t)((cn) * 2048 + b * 64 + hh)) * 4096 +             \
                    j * 1024 + lane * 16,                                        \
                (fdst) + row * FROW + 64 + j * 1024);                            \
    } else {                                                                     \
      int t = u - 40;                                                            \
      int tap = t >> 2, part = t & 3;                                            \
      gload16(wpkB + (size_t)((cn) * 9 + tap) * 4096 + part * 1024 + lane * 16,  \
              (bdst) + tap * 4096 + part * 1024);                                \
    }                                                                            \
  }

  STAGE_GRP(0, smem, smem + 2 * FBUF);
  __syncthreads();

  f32x4 acc[2][4][4];
#pragma unroll
  for (int ro = 0; ro < 2; ++ro)
#pragma unroll
    for (int cfi = 0; cfi < 4; ++cfi)
#pragma unroll
      for (int nf = 0; nf < 4; ++nf)
#pragma unroll
        for (int qq = 0; qq < 4; ++qq) acc[ro][cfi][nf][qq] = 0.0f;

#define COMP_TAP(T)                                                              \
  {                                                                              \
    const int kh_ = (T) / 3, kw_ = (T) % 3;                                      \
    bf16x8 A[2][4], Bv[4];                                                       \
    _Pragma("unroll")                                                            \
    for (int ro = 0; ro < 2; ++ro) {                                             \
      const char* rp = f + (rowb + ro + kh_) * FROW;                             \
      _Pragma("unroll")                                                          \
      for (int cfi = 0; cfi < 4; ++cfi)                                          \
        A[ro][cfi] = *(const bf16x8*)(rp + aoff[cfi][kw_]);                      \
    }                                                                            \
    _Pragma("unroll")                                                            \
    for (int nf = 0; nf < 4; ++nf)                                               \
      Bv[nf] = *(const bf16x8*)(bgc + (T) * 4096 + boff[nf]);                    \
    _Pragma("unroll")                                                            \
    for (int ro = 0; ro < 2; ++ro)                                               \
      _Pragma("unroll")                                                          \
      for (int cfi = 0; cfi < 4; ++cfi)                                          \
        _Pragma("unroll")                                                        \
        for (int nf = 0; nf < 4; ++nf)                                           \
          acc[ro][cfi][nf] = __builtin_amdgcn_mfma_f32_16x16x32_bf16(            \
              A[ro][cfi], Bv[nf], acc[ro][cfi][nf], 0, 0, 0);                    \
  }

  for (int c2 = 0; c2 < 14; ++c2) {
    const int cur = c2 & 1;
    const char* f = smem + (cur ? FBUF : 0);
    const char* bgc = smem + 2 * FBUF + (cur ? BGRP : 0);
    if (c2 < 13) {
      char* fnext = smem + (cur ? 0 : FBUF);
      char* bnext = smem + 2 * FBUF + (cur ? 0 : BGRP);
      STAGE_GRP(c2 + 1, fnext, bnext);
    }
    if (grp == 0) {
      COMP_TAP(0) COMP_TAP(1) COMP_TAP(2) COMP_TAP(3) COMP_TAP(4)
    } else {
      COMP_TAP(5) COMP_TAP(6) COMP_TAP(7) COMP_TAP(8)
    }
    __syncthreads();
  }
#undef COMP_TAP
#undef STAGE_GRP

  // cross-group reduction: partials in LDS as [co(64)][pxl(512)] f32, px-XOR
  // swizzled by (co&7)<<2 (uniform 8 lanes per 16B slot -> conflict-free).
  if (grp == 1) {
#pragma unroll
    for (int ro = 0; ro < 2; ++ro)
#pragma unroll
      for (int cfi = 0; cfi < 4; ++cfi)
#pragma unroll
        for (int nf = 0; nf < 4; ++nf) {
          int co = nf * 16 + l15;
          int pxl = (rowb + ro) * 64 + cfi * 16 + (lg << 2);
          float* p = (float*)smem + co * 512 + (pxl ^ ((co & 7) << 2));
          *(f32x4*)p = acc[ro][cfi][nf];
        }
  }
  __syncthreads();
  if (grp == 0) {
#pragma unroll
    for (int ro = 0; ro < 2; ++ro) {
      const int h = h0 + rowb + ro;
#pragma unroll
      for (int cfi = 0; cfi < 4; ++cfi) {
        int w4 = cfi * 16 + (lg << 2);
#pragma unroll
        for (int nf = 0; nf < 4; ++nf) {
          int co = nf * 16 + l15;
          int pxl = (rowb + ro) * 64 + cfi * 16 + (lg << 2);
          const float* p = (const float*)smem + co * 512 + (pxl ^ ((co & 7) << 2));
          f32x4 part = *(const f32x4*)p;
          float bv = bias[co];
          f32x4 v = acc[ro][cfi][nf];
          f32x4 res;
          res[0] = v[0] + part[0] + bv;
          res[1] = v[1] + part[1] + bv;
          res[2] = v[2] + part[2] + bv;
          res[3] = v[3] + part[3] + bv;
          *(f32x4*)(out + ((size_t)(b * 64 + co) * 64 + h) * 64 + w4) = res;
        }
      }
    }
  }
}

// ---------------- fallback: naive fp32 direct (if ws too small) ----------------
__global__ void naive_k(const float* __restrict__ x, const float* __restrict__ sb,
                        const float* __restrict__ ss, const float* __restrict__ cf,
                        const float* __restrict__ bias, float* __restrict__ out) {
  int idx = blockIdx.x * 256 + threadIdx.x;
  if (idx >= 32 * 64 * 64 * 64) return;
  int w = idx & 63, h = (idx >> 6) & 63, co = (idx >> 12) & 63, b = idx >> 18;
  float acc = bias[co];
  for (int ci = 0; ci < 64; ++ci) {
    for (int kh = 0; kh < 3; ++kh) {
      int hh = h + kh - 1;
      if ((unsigned)hh >= 64u) continue;
      for (int kw = 0; kw < 3; ++kw) {
        int ww = w + kw - 1;
        if ((unsigned)ww >= 64u) continue;
        float v = x[((b * 64 + ci) * 64 + hh) * 64 + ww];
        int wi = ((co * 64 + ci) * 3 + kh) * 3 + kw;
        float s1, c1; __sincosf(v, &s1, &c1);
        float c2 = c1 * c1 - s1 * s1, s2 = 2.f * s1 * c1;
        float c3 = c1 * c2 - s1 * s2, s3 = s1 * c2 + c1 * s2;
        float t = sb[wi] * (v / (1.f + __expf(-v)));
        t += ss[wi] * (cf[wi * 3] * c1 + cf[wi * 3 + 1] * c2 + cf[wi * 3 + 2] * c3 +
                       cf[(36864 + wi) * 3] * s1 + cf[(36864 + wi) * 3 + 1] * s2 +
                       cf[(36864 + wi) * 3 + 2] * s3);
        acc += t;
      }
    }
  }
  out[idx] = acc;
}

extern "C" void kernel_launch(void* const* d_in, const int* in_sizes, int n_in,
                              void* d_out, int out_size, void* d_ws, size_t ws_size,
                              hipStream_t stream) {
  const float* x = (const float*)d_in[0];
  const float* sb = (const float*)d_in[1];
  const float* ss = (const float*)d_in[2];
  const float* cf = (const float*)d_in[3];
  const float* bias = (const float*)d_in[4];
  float* out = (float*)d_out;

  const size_t FEATS_OFF = 1u << 20;                          // wpk in first 1 MB
  const size_t NEED = FEATS_OFF + (size_t)14 * 32 * 64 * 4096; // ~118.5 MB
  if (ws_size >= NEED) {
    unsigned short* wpk = (unsigned short*)d_ws;
    unsigned short* fg = (unsigned short*)((char*)d_ws + FEATS_OFF);
    pack_w_k<<<1008, 256, 0, stream>>>(sb, ss, cf, wpk);
    feats_k<<<dim3(32, 64), 256, 0, stream>>>(x, fg);
    (void)hipFuncSetAttribute((const void*)gemm_k,
                              hipFuncAttributeMaxDynamicSharedMemorySize, LDS_TOT);
    gemm_k<<<dim3(32, 8), 512, LDS_TOT, stream>>>(fg, wpk, bias, out);
  } else {
    naive_k<<<32768, 256, 0, stream>>>(x, sb, ss, cf, bias, out);
  }
}